// Round 4
// baseline (205.109 us; speedup 1.0000x reference)
//
#include <hip/hip_runtime.h>
#include <hip/hip_bf16.h>

// CostAttention on MI355X — round 17: producer/consumer wave specialization.
// R16 post-mortem: loop rotation was a no-op (identical counters) — limiter is
// structural. Corrected cycle model: 16x16x32 bf16 MFMA ~16 cyc/SIMD (2.5PF
// dense), total MFMA work = 35.6us at 100% pipe -> measured 105us == 36%
// MfmaUtil exactly. MFMA starvation from serial S->softmax->P-LDS->PV chain at
// 2 waves/SIMD (120 VGPR + 80 acc ~ 200 unified regs).
// Fix: split roles. Waves 0-3 produce (S 48 MFMA + softmax -> P tile in LDS,
// state: kfh/kfl+a0a1, Q read from LDS, ~90 regs). Waves 4-7 consume (PV+l
// 20 MFMA, state: oacc+lacc+vfh+pf, ~120 regs). Both <=128 ->
// __launch_bounds__(512,2) -> 4 waves/SIMD, 2 blocks/CU, 400 blocks all
// co-resident; P/C anti-phase overlaps VALU with MFMA.
// Pair p = w&3 handles m-chunks [50p, 50p+50); per-pair double-buffered P in
// LDS; 51 lockstep steps with one block barrier each (prod t<50, cons t>=1).
// Numerics per chunk identical; only accumulation order changes (~1e-6).
//
// ws layout: shorts [Qh][Ql][Kh][Kl][Vh], each SZ = 1,638,400 shorts (16.4MB).
//   Q/K chunk  ((b*400+mi)*2+c0)*512 + lane*8 : elem [r=16mi+l16][c=32c0+8qq+j]
//   V   chunk  (((b*100+i64)*8)+ct*2+mh)*512 + lane*8 : elem [c=16ct+l16][m=64i64+32mh+8qq+j]

#define NPIX 6400
#define SZ 1638400
#define SHIFT2 11.541560327111707f   // 8 * log2(e)

typedef float f32x4 __attribute__((ext_vector_type(4)));
typedef short bf16x8 __attribute__((ext_vector_type(8)));

#if defined(__has_builtin)
#if __has_builtin(__builtin_amdgcn_exp2f)
#define EXP2(x) __builtin_amdgcn_exp2f(x)
#endif
#endif
#ifndef EXP2
#define EXP2(x) exp2f(x)
#endif

__device__ __forceinline__ void split2(float x, short& h, short& l) {
  unsigned xb = __float_as_uint(x);
  h = (short)(xb >> 16);
  float r = x - __uint_as_float(xb & 0xffff0000u);
  l = (short)(__float_as_uint(r) >> 16);
}

__device__ __forceinline__ short rne_bf16(float x) {
  unsigned u = __float_as_uint(x);
  return (short)((u + 0x7fffu + ((u >> 16) & 1u)) >> 16);
}

__device__ __forceinline__ unsigned pk2(float a, float b) {
  __hip_bfloat162 t = __float22bfloat162_rn(make_float2(a, b));
  unsigned r;
  __builtin_memcpy(&r, &t, 4);
  return r;
}

// ---------------- prep (unchanged): stage -> LDS -> frag gather -------------
// grid 1000: [0,400) K (b,m-tile) | [400,800) Q-proj (b,r-tile) | [800,1000) V
__global__ __launch_bounds__(256, 2) void prep(
    const float* __restrict__ query, const float* __restrict__ keys,
    const float* __restrict__ values, const float* __restrict__ Wq,
    const float* __restrict__ bq, short* __restrict__ ws)
{
  const int tid = threadIdx.x;
  const int w = tid >> 6;
  const int lane = tid & 63, l16 = lane & 15, qq = lane >> 4;
  short* Qh = ws;          short* Ql = ws + SZ;
  short* Kh = ws + 2 * SZ; short* Kl = ws + 3 * SZ;
  short* Vh = ws + 4 * SZ;
  const int x = blockIdx.x;

  __shared__ float T[64 * 65];

  if (x < 400) {                      // ---- K split (trunc hi/lo, 3-term S)
    const int b = x / 100, t64 = x % 100;
    const int m0 = t64 * 64;
    const float* kb = keys + (size_t)b * 64 * NPIX;
    {
      const int ch = tid >> 2, ml = (tid & 3) * 4;
      const float* src = kb + (size_t)ch * NPIX + m0 + ml;
      #pragma unroll
      for (int u = 0; u < 4; ++u)
        *(float4*)&T[ch * 65 + ml + 16 * u] = *(const float4*)(src + 16 * u);
    }
    __syncthreads();
    const int mi = t64 * 4 + w;
    #pragma unroll
    for (int c0 = 0; c0 < 2; ++c0) {
      float t[8];
      #pragma unroll
      for (int j = 0; j < 8; ++j)
        t[j] = T[(32 * c0 + 8 * qq + j) * 65 + 16 * w + l16];
      bf16x8 h8, l8;
      #pragma unroll
      for (int j = 0; j < 8; ++j) { short h, l; split2(t[j], h, l); h8[j] = h; l8[j] = l; }
      const int off = ((b * 400 + mi) * 2 + c0) * 512 + lane * 8;
      *(bf16x8*)(Kh + off) = h8;
      *(bf16x8*)(Kl + off) = l8;
    }
  } else if (x < 800) {               // ---- Q projection + trunc hi/lo split
    const int y = x - 400;
    const int b = y / 100, t64 = y % 100;
    const int r0 = t64 * 64;
    const float* qb = query + (size_t)b * 64 * NPIX;
    {
      const int ch = tid >> 2, ml = (tid & 3) * 4;
      const float* src = qb + (size_t)ch * NPIX + r0 + ml;
      #pragma unroll
      for (int u = 0; u < 4; ++u)
        *(float4*)&T[ch * 65 + ml + 16 * u] = *(const float4*)(src + 16 * u);
    }
    __syncthreads();
    const int mi = t64 * 4 + w;

    float acc[2][8];
    #pragma unroll
    for (int c0 = 0; c0 < 2; ++c0)
      #pragma unroll
      for (int j = 0; j < 8; ++j) acc[c0][j] = 0.f;

    for (int cin4 = 0; cin4 < 64; cin4 += 4) {
      float xv[4];
      #pragma unroll
      for (int u = 0; u < 4; ++u)
        xv[u] = T[(cin4 + u) * 65 + 16 * w + l16];
      #pragma unroll
      for (int c0 = 0; c0 < 2; ++c0)
        #pragma unroll
        for (int j = 0; j < 8; ++j) {
          const float4 wv = *(const float4*)&Wq[(32 * c0 + 8 * qq + j) * 64 + cin4];
          acc[c0][j] += wv.x * xv[0] + wv.y * xv[1] + wv.z * xv[2] + wv.w * xv[3];
        }
    }
    #pragma unroll
    for (int c0 = 0; c0 < 2; ++c0) {
      bf16x8 h8, l8;
      #pragma unroll
      for (int j = 0; j < 8; ++j) {
        // scale = (1/8)*log2(e): S in log2 domain -> raw exp2 in main
        float v = (acc[c0][j] + bq[32 * c0 + 8 * qq + j]) * 0.18033688011112042f;
        short h, l; split2(v, h, l);
        h8[j] = h; l8[j] = l;
      }
      const int off = ((b * 400 + mi) * 2 + c0) * 512 + lane * 8;
      *(bf16x8*)(Qh + off) = h8;
      *(bf16x8*)(Ql + off) = l8;
    }
  } else {                            // ---- V: RNE bf16, hi only
    const int gw = (x - 800) * 4 + w;
    const int b = gw / 200, rest = gw % 200;
    const int i = rest / 2, half = rest % 2;
    const float* vb = values + (size_t)b * 64 * NPIX;
    #pragma unroll
    for (int cc = 0; cc < 2; ++cc) {
      const int ct = 2 * half + cc;
      #pragma unroll
      for (int mh = 0; mh < 2; ++mh) {
        const float* vp = vb + (size_t)(16 * ct + l16) * NPIX + 64 * i + 32 * mh + 8 * qq;
        const float4 a  = *(const float4*)vp;
        const float4 b4 = *(const float4*)(vp + 4);
        const float t[8] = {a.x, a.y, a.z, a.w, b4.x, b4.y, b4.z, b4.w};
        bf16x8 h8;
        #pragma unroll
        for (int j = 0; j < 8; ++j) h8[j] = rne_bf16(t[j]);
        const int off = (((b * 100 + i) * 8) + ct * 2 + mh) * 512 + lane * 8;
        *(bf16x8*)(Vh + off) = h8;
      }
    }
  }
}

// ---------------- main: 400 blocks x 512 thr; 4 producer + 4 consumer waves -
// LDS map (bytes): PB [4 pairs][2 bufs][4096]   = 32768  @ 0
//                  QH [8 frag][64 lane][16B]    =  8192  @ 32768
//                  QL same                      =  8192  @ 40960
//                  LST [4 pairs][64] f32        =  1024  @ 49152
//                  OC [64][65] f32 (16640B) aliases PB after the loop.
__global__ __launch_bounds__(512, 2) void attn_main(
    const short* __restrict__ ws, float* __restrict__ out)
{
  const int tid  = threadIdx.x;
  const int w    = tid >> 6;
  const int lane = tid & 63;
  const int l16  = lane & 15, qq = lane >> 4;
  const int x = blockIdx.x;
  const int b      = x & 3;           // batch -> XCDs {b, b+4}; KV 2.4MB < L2
  const int rowjob = x >> 2;          // 0..99
  const int rb     = rowjob * 64;

  const short* Qh = ws;
  const short* Kh = ws + 2 * SZ;
  const short* Vh = ws + 4 * SZ;
  float* ob = out + (size_t)b * 64 * NPIX;

  __shared__ char smem[50176];
  short* PB  = (short*)smem;                 // pair p buf k: + (p*2+k)*2048 shorts
  short* QH  = ((short*)smem) + 16384;       // byte 32768
  short* QL  = ((short*)smem) + 20480;       // byte 40960
  float* LST = (float*)(smem + 49152);       // [4][64]
  float* OC  = (float*)smem;                 // alias PB (combine phase)

  // stage Q hi/lo frags into LDS (8x redundant across waves, benign)
  {
    const short* qp = Qh + (size_t)((b * 400 + rowjob * 4) * 2) * 512 + lane * 8;
    #pragma unroll
    for (int s = 0; s < 4; ++s)
      #pragma unroll
      for (int c0 = 0; c0 < 2; ++c0) {
        *(bf16x8*)(QH + ((s * 2 + c0) * 64 + lane) * 8) =
            *(const bf16x8*)(qp + (s * 2 + c0) * 512);
        *(bf16x8*)(QL + ((s * 2 + c0) * 64 + lane) * 8) =
            *(const bf16x8*)(qp + SZ + (s * 2 + c0) * 512);
      }
  }
  __syncthreads();

  const int  p     = w & 3;           // pair id (producer w, consumer w-4)
  const bool isP   = (w < 4);
  const int  cbase = p * 50;          // pair p owns m-chunks [50p, 50p+50)

  f32x4 zero4 = {0.f, 0.f, 0.f, 0.f};
  f32x4 oacc[4][4];
  f32x4 lacc[4];
  #pragma unroll
  for (int ct = 0; ct < 4; ++ct)
    #pragma unroll
    for (int s = 0; s < 4; ++s) oacc[ct][s] = zero4;
  #pragma unroll
  for (int s = 0; s < 4; ++s) lacc[s] = zero4;

  bf16x8 onesA;
  #pragma unroll
  for (int j = 0; j < 8; ++j) onesA[j] = (short)0x3F80;

  bf16x8 kfh[2][2], kfl[2][2];
  bf16x8 vfh[4];

  auto loadK = [&](int i2) {
    const short* kp = Kh + (size_t)((b * 400 + 2 * i2) * 2) * 512 + lane * 8;
    #pragma unroll
    for (int mt = 0; mt < 2; ++mt)
      #pragma unroll
      for (int c0 = 0; c0 < 2; ++c0) {
        kfh[mt][c0] = *(const bf16x8*)(kp + (mt * 2 + c0) * 512);
        kfl[mt][c0] = *(const bf16x8*)(kp + SZ + (mt * 2 + c0) * 512);
      }
  };
  auto loadV = [&](int i2) {
    const short* vp = Vh + (size_t)((b * 100 + (i2 >> 1)) * 8) * 512 + lane * 8;
    #pragma unroll
    for (int ct = 0; ct < 4; ++ct)
      vfh[ct] = *(const bf16x8*)(vp + (ct * 2 + (i2 & 1)) * 512);
  };

  if (isP) loadK(cbase);
  else     loadV(cbase);

  // ---- lockstep pipeline: producer fills PB[p][t&1], consumer drains t-1 ----
  for (int t = 0; t <= 50; ++t) {
    if (isP) {
      if (t < 50) {
        const int c = cbase + t;
        short* PW = PB + ((p * 2 + (t & 1)) << 11);
        f32x4 a0[4], a1[4];
        #pragma unroll
        for (int s = 0; s < 4; ++s) {
          f32x4 t0 = zero4, t1 = zero4;
          #pragma unroll
          for (int c0 = 0; c0 < 2; ++c0) {
            const bf16x8 qh = *(const bf16x8*)(QH + ((s * 2 + c0) * 64 + lane) * 8);
            const bf16x8 ql = *(const bf16x8*)(QL + ((s * 2 + c0) * 64 + lane) * 8);
            t0 = __builtin_amdgcn_mfma_f32_16x16x32_bf16(kfh[0][c0], qh, t0, 0, 0, 0);
            t0 = __builtin_amdgcn_mfma_f32_16x16x32_bf16(kfh[0][c0], ql, t0, 0, 0, 0);
            t0 = __builtin_amdgcn_mfma_f32_16x16x32_bf16(kfl[0][c0], qh, t0, 0, 0, 0);
            t1 = __builtin_amdgcn_mfma_f32_16x16x32_bf16(kfh[1][c0], qh, t1, 0, 0, 0);
            t1 = __builtin_amdgcn_mfma_f32_16x16x32_bf16(kfh[1][c0], ql, t1, 0, 0, 0);
            t1 = __builtin_amdgcn_mfma_f32_16x16x32_bf16(kfl[1][c0], qh, t1, 0, 0, 0);
          }
          a0[s] = t0; a1[s] = t1;
        }
        loadK(t < 49 ? c + 1 : cbase);   // prefetch next K (clamp at tail)
        #pragma unroll
        for (int s = 0; s < 4; ++s) {
          float p0 = EXP2(a0[s][0] - SHIFT2), p1 = EXP2(a0[s][1] - SHIFT2);
          float p2 = EXP2(a0[s][2] - SHIFT2), p3 = EXP2(a0[s][3] - SHIFT2);
          float p4 = EXP2(a1[s][0] - SHIFT2), p5 = EXP2(a1[s][1] - SHIFT2);
          float p6 = EXP2(a1[s][2] - SHIFT2), p7 = EXP2(a1[s][3] - SHIFT2);
          union { unsigned u[2]; short4 s4; } ua, ub;
          ua.u[0] = pk2(p0, p1); ua.u[1] = pk2(p2, p3);
          ub.u[0] = pk2(p4, p5); ub.u[1] = pk2(p6, p7);
          const int gbase = (s * 4 + (qq >> 1)) * 16 + l16;
          *(short4*)(PW + (gbase * 8 + 4 * (qq & 1))) = ua.s4;
          *(short4*)(PW + ((gbase + 32) * 8 + 4 * (qq & 1))) = ub.s4;
        }
      }
    } else {
      if (t >= 1) {
        const short* PR = PB + ((p * 2 + ((t - 1) & 1)) << 11);
        bf16x8 pf[4];
        #pragma unroll
        for (int s = 0; s < 4; ++s)
          pf[s] = *(const bf16x8*)(PR + (((s * 4 + qq) * 16 + l16) * 8));
        #pragma unroll
        for (int ct = 0; ct < 4; ++ct)
          #pragma unroll
          for (int s = 0; s < 4; ++s)
            oacc[ct][s] = __builtin_amdgcn_mfma_f32_16x16x32_bf16(vfh[ct], pf[s], oacc[ct][s], 0, 0, 0);
        #pragma unroll
        for (int s = 0; s < 4; ++s)
          lacc[s] = __builtin_amdgcn_mfma_f32_16x16x32_bf16(onesA, pf[s], lacc[s], 0, 0, 0);
        loadV(t < 50 ? cbase + t : cbase);   // prefetch next V (clamp at tail)
      }
    }
    __syncthreads();
  }

  // ---------------- combine across the 4 pairs (consumer partials) ----------
  if (!isP && qq == 0) {
    #pragma unroll
    for (int s = 0; s < 4; ++s) LST[p * 64 + s * 16 + l16] = lacc[s][0];
  }

  #pragma unroll
  for (int wp = 0; wp < 4; ++wp) {
    if (w == 4 + wp) {
      #pragma unroll
      for (int ct = 0; ct < 4; ++ct)
        #pragma unroll
        for (int s = 0; s < 4; ++s)
          #pragma unroll
          for (int r = 0; r < 4; ++r) {
            const int c = 16 * ct + 4 * qq + r;
            const int idx = c * 65 + 16 * s + l16;
            if (wp == 0) OC[idx] = oacc[ct][s][r];
            else         OC[idx] += oacc[ct][s][r];
          }
    }
    __syncthreads();
  }

  // final scale + coalesced store: 512 threads, 8 channels each
  {
    const int r  = tid & 63;
    const int cg = tid >> 6;          // 0..7
    float lsum = 0.f;
    #pragma unroll
    for (int w2 = 0; w2 < 4; ++w2)
      lsum += LST[w2 * 64 + (r >> 4) * 16 + (r & 15)];
    const float inv = 1.0f / lsum;
    #pragma unroll
    for (int u = 0; u < 8; ++u) {
      const int c = cg * 8 + u;
      ob[(size_t)c * NPIX + rb + r] = OC[c * 65 + r] * inv;
    }
  }
}

extern "C" void kernel_launch(void* const* d_in, const int* in_sizes, int n_in,
                              void* d_out, int out_size, void* d_ws, size_t ws_size,
                              hipStream_t stream) {
  const float* query  = (const float*)d_in[0];
  const float* keys   = (const float*)d_in[1];
  const float* values = (const float*)d_in[2];
  const float* Wq     = (const float*)d_in[3];
  const float* bq     = (const float*)d_in[4];
  short* ws = (short*)d_ws;           // 5*SZ*2 = 16.4 MB
  prep<<<dim3(1000), dim3(256), 0, stream>>>(query, keys, values, Wq, bq, ws);
  attn_main<<<dim3(400), dim3(512), 0, stream>>>(ws, (float*)d_out);
}

// Round 6
// 184.142 us; speedup vs baseline: 1.1139x; 1.1139x over previous
//
#include <hip/hip_runtime.h>
#include <hip/hip_bf16.h>

// CostAttention on MI355X — round 19 (= R18 with LDS overflow fix).
// R18 post-mortem: FAILED correctness — smem was 33792 B but LST ([8][64] f32
// = 2048 B at offset 32768) needs 34816 B. Waves 4-7 wrote 1 KB OOB -> UB in
// lsum -> absmax 9.8e-3 / 468 across runs. The two optimizations themselves
// are value-identity transforms; re-testing with smem[34816].
//  1) prep: Wq staged in LDS once per Q-block (was 256 global reads/thread,
//     ~400 GB L2 traffic; prep ~75us inferred from total 183 - attn 105).
//  2) attn_main: Q-lo in registers (qfl, +32 VGPR; ~224 unified regs still
//     within the 2 waves/SIMD occupancy that oacc pins anyway). Loop LDS ops
//     are now only the P round-trip (8 st + 4 ld per chunk).
//
// ws layout: shorts [Qh][Ql][Kh][Kl][Vh], each SZ = 1,638,400 shorts (16.4MB).
//   Q/K chunk  ((b*400+mi)*2+c0)*512 + lane*8 : elem [r=16mi+l16][c=32c0+8qq+j]
//   V   chunk  (((b*100+i64)*8)+ct*2+mh)*512 + lane*8 : elem [c=16ct+l16][m=64i64+32mh+8qq+j]

#define NPIX 6400
#define SZ 1638400
#define SHIFT2 11.541560327111707f   // 8 * log2(e)

typedef float f32x4 __attribute__((ext_vector_type(4)));
typedef short bf16x8 __attribute__((ext_vector_type(8)));

#if defined(__has_builtin)
#if __has_builtin(__builtin_amdgcn_sched_barrier)
#define SCHED_FENCE() __builtin_amdgcn_sched_barrier(0)
#endif
#if __has_builtin(__builtin_amdgcn_exp2f)
#define EXP2(x) __builtin_amdgcn_exp2f(x)
#endif
#endif
#ifndef SCHED_FENCE
#define SCHED_FENCE()
#endif
#ifndef EXP2
#define EXP2(x) exp2f(x)
#endif

__device__ __forceinline__ void split2(float x, short& h, short& l) {
  unsigned xb = __float_as_uint(x);
  h = (short)(xb >> 16);
  float r = x - __uint_as_float(xb & 0xffff0000u);
  l = (short)(__float_as_uint(r) >> 16);
}

__device__ __forceinline__ short rne_bf16(float x) {
  unsigned u = __float_as_uint(x);
  return (short)((u + 0x7fffu + ((u >> 16) & 1u)) >> 16);
}

__device__ __forceinline__ unsigned pk2(float a, float b) {
  __hip_bfloat162 t = __float22bfloat162_rn(make_float2(a, b));
  unsigned r;
  __builtin_memcpy(&r, &t, 4);
  return r;
}

// ---------------- prep: stage -> LDS -> frag gather -------------------------
// grid 1000: [0,400) K (b,m-tile) | [400,800) Q-proj (b,r-tile) | [800,1000) V
// Wq staged in LDS for the Q phase (was: 256 global loads/thread).
__global__ __launch_bounds__(256, 2) void prep(
    const float* __restrict__ query, const float* __restrict__ keys,
    const float* __restrict__ values, const float* __restrict__ Wq,
    const float* __restrict__ bq, short* __restrict__ ws)
{
  const int tid = threadIdx.x;
  const int w = tid >> 6;
  const int lane = tid & 63, l16 = lane & 15, qq = lane >> 4;
  short* Qh = ws;          short* Ql = ws + SZ;
  short* Kh = ws + 2 * SZ; short* Kl = ws + 3 * SZ;
  short* Vh = ws + 4 * SZ;
  const int x = blockIdx.x;

  __shared__ float T[64 * 65];
  __shared__ float WQ[64 * 64];   // Q phase only; 16 KB

  if (x < 400) {                      // ---- K split (trunc hi/lo, 3-term S)
    const int b = x / 100, t64 = x % 100;
    const int m0 = t64 * 64;
    const float* kb = keys + (size_t)b * 64 * NPIX;
    {
      const int ch = tid >> 2, ml = (tid & 3) * 4;
      const float* src = kb + (size_t)ch * NPIX + m0 + ml;
      #pragma unroll
      for (int u = 0; u < 4; ++u)
        *(float4*)&T[ch * 65 + ml + 16 * u] = *(const float4*)(src + 16 * u);
    }
    __syncthreads();
    const int mi = t64 * 4 + w;
    #pragma unroll
    for (int c0 = 0; c0 < 2; ++c0) {
      float t[8];
      #pragma unroll
      for (int j = 0; j < 8; ++j)
        t[j] = T[(32 * c0 + 8 * qq + j) * 65 + 16 * w + l16];
      bf16x8 h8, l8;
      #pragma unroll
      for (int j = 0; j < 8; ++j) { short h, l; split2(t[j], h, l); h8[j] = h; l8[j] = l; }
      const int off = ((b * 400 + mi) * 2 + c0) * 512 + lane * 8;
      *(bf16x8*)(Kh + off) = h8;
      *(bf16x8*)(Kl + off) = l8;
    }
  } else if (x < 800) {               // ---- Q projection + trunc hi/lo split
    const int y = x - 400;
    const int b = y / 100, t64 = y % 100;
    const int r0 = t64 * 64;
    const float* qb = query + (size_t)b * 64 * NPIX;
    {
      const int ch = tid >> 2, ml = (tid & 3) * 4;
      const float* src = qb + (size_t)ch * NPIX + r0 + ml;
      #pragma unroll
      for (int u = 0; u < 4; ++u)
        *(float4*)&T[ch * 65 + ml + 16 * u] = *(const float4*)(src + 16 * u);
    }
    {   // stage Wq (64x64 f32) into LDS, coalesced
      const float4* wsrc = (const float4*)Wq;
      float4* wdst = (float4*)WQ;
      #pragma unroll
      for (int u = 0; u < 4; ++u)
        wdst[tid + 256 * u] = wsrc[tid + 256 * u];
    }
    __syncthreads();
    const int mi = t64 * 4 + w;

    float acc[2][8];
    #pragma unroll
    for (int c0 = 0; c0 < 2; ++c0)
      #pragma unroll
      for (int j = 0; j < 8; ++j) acc[c0][j] = 0.f;

    for (int cin4 = 0; cin4 < 64; cin4 += 4) {
      float xv[4];
      #pragma unroll
      for (int u = 0; u < 4; ++u)
        xv[u] = T[(cin4 + u) * 65 + 16 * w + l16];
      #pragma unroll
      for (int c0 = 0; c0 < 2; ++c0)
        #pragma unroll
        for (int j = 0; j < 8; ++j) {
          const float4 wv = *(const float4*)&WQ[(32 * c0 + 8 * qq + j) * 64 + cin4];
          acc[c0][j] += wv.x * xv[0] + wv.y * xv[1] + wv.z * xv[2] + wv.w * xv[3];
        }
    }
    #pragma unroll
    for (int c0 = 0; c0 < 2; ++c0) {
      bf16x8 h8, l8;
      #pragma unroll
      for (int j = 0; j < 8; ++j) {
        // scale = (1/8)*log2(e): S in log2 domain -> raw exp2 in main
        float v = (acc[c0][j] + bq[32 * c0 + 8 * qq + j]) * 0.18033688011112042f;
        short h, l; split2(v, h, l);
        h8[j] = h; l8[j] = l;
      }
      const int off = ((b * 400 + mi) * 2 + c0) * 512 + lane * 8;
      *(bf16x8*)(Qh + off) = h8;
      *(bf16x8*)(Ql + off) = l8;
    }
  } else {                            // ---- V: RNE bf16, hi only
    const int gw = (x - 800) * 4 + w;
    const int b = gw / 200, rest = gw % 200;
    const int i = rest / 2, half = rest % 2;
    const float* vb = values + (size_t)b * 64 * NPIX;
    #pragma unroll
    for (int cc = 0; cc < 2; ++cc) {
      const int ct = 2 * half + cc;
      #pragma unroll
      for (int mh = 0; mh < 2; ++mh) {
        const float* vp = vb + (size_t)(16 * ct + l16) * NPIX + 64 * i + 32 * mh + 8 * qq;
        const float4 a  = *(const float4*)vp;
        const float4 b4 = *(const float4*)(vp + 4);
        const float t[8] = {a.x, a.y, a.z, a.w, b4.x, b4.y, b4.z, b4.w};
        bf16x8 h8;
        #pragma unroll
        for (int j = 0; j < 8; ++j) h8[j] = rne_bf16(t[j]);
        const int off = (((b * 100 + i) * 8) + ct * 2 + mh) * 512 + lane * 8;
        *(bf16x8*)(Vh + off) = h8;
      }
    }
  }
}

// ---------------- main: 400 blocks x 512 thr; 8-wave in-block m-split -------
// R14 structure; Q-hi AND Q-lo in registers. Loop LDS = P round-trip only.
// LDS: P (8 x 4 KB) = 32768 | LST [8][64] f32 = 2048 @ 32768 -> smem 34816.
// OC [64][65] f32 (16640 B) aliases P after the loop.
__global__ __launch_bounds__(512, 1) void attn_main(
    const short* __restrict__ ws, float* __restrict__ out)
{
  const int tid  = threadIdx.x;
  const int w    = tid >> 6;          // wave 0..7 = m-eighth
  const int lane = tid & 63;
  const int l16  = lane & 15, qq = lane >> 4;
  const int x = blockIdx.x;
  const int b      = x & 3;           // batch -> XCDs {b, b+4}; KV 2.4MB < L2
  const int rowjob = x >> 2;          // 0..99
  const int rb     = rowjob * 64;

  const short* Qh = ws;
  const short* Kh = ws + 2 * SZ;
  const short* Vh = ws + 4 * SZ;
  float* ob = out + (size_t)b * 64 * NPIX;

  __shared__ char smem[34816];
  short* P   = ((short*)smem) + (w << 11);   // wave-private 2048 shorts
  float* OC  = (float*)smem;
  float* LST = (float*)(smem + 32768);       // [8 waves][4 strips][16] = 2 KB

  bf16x8 qfh[4][2], qfl[4][2];
  {
    const short* qp = Qh + (size_t)((b * 400 + rowjob * 4) * 2) * 512 + lane * 8;
    #pragma unroll
    for (int s = 0; s < 4; ++s)
      #pragma unroll
      for (int c0 = 0; c0 < 2; ++c0) {
        qfh[s][c0] = *(const bf16x8*)(qp + (s * 2 + c0) * 512);
        qfl[s][c0] = *(const bf16x8*)(qp + SZ + (s * 2 + c0) * 512);
      }
  }

  f32x4 zero4 = {0.f, 0.f, 0.f, 0.f};
  f32x4 oacc[4][4];
  f32x4 lacc[4];
  #pragma unroll
  for (int ct = 0; ct < 4; ++ct)
    #pragma unroll
    for (int s = 0; s < 4; ++s) oacc[ct][s] = zero4;
  #pragma unroll
  for (int s = 0; s < 4; ++s) lacc[s] = zero4;

  bf16x8 onesA;
  #pragma unroll
  for (int j = 0; j < 8; ++j) onesA[j] = (short)0x3F80;

  bf16x8 kfh[2][2], kfl[2][2];
  bf16x8 vfh[4];

  auto loadK = [&](int i2) {
    const short* kp = Kh + (size_t)((b * 400 + 2 * i2) * 2) * 512 + lane * 8;
    #pragma unroll
    for (int mt = 0; mt < 2; ++mt)
      #pragma unroll
      for (int c0 = 0; c0 < 2; ++c0) {
        kfh[mt][c0] = *(const bf16x8*)(kp + (mt * 2 + c0) * 512);
        kfl[mt][c0] = *(const bf16x8*)(kp + SZ + (mt * 2 + c0) * 512);
      }
  };
  auto loadV = [&](int i2) {
    const short* vp = Vh + (size_t)((b * 100 + (i2 >> 1)) * 8) * 512 + lane * 8;
    #pragma unroll
    for (int ct = 0; ct < 4; ++ct)
      vfh[ct] = *(const bf16x8*)(vp + (ct * 2 + (i2 & 1)) * 512);
  };

  // wave w owns m-chunks [25w, 25w+25) of 32 m each
  const int i0 = w * 25;
  loadK(i0);
  loadV(i0);

  for (int it = 0; it < 25; ++it) {
    const int i2 = i0 + it;
    const int inext = (it == 24) ? i0 : i2 + 1;

    // ---- all strips' S-MFMAs first (4 independent chains), all-reg operands
    f32x4 a0[4], a1[4];
    #pragma unroll
    for (int s = 0; s < 4; ++s) {
      f32x4 t0 = zero4, t1 = zero4;
      #pragma unroll
      for (int c0 = 0; c0 < 2; ++c0) {
        t0 = __builtin_amdgcn_mfma_f32_16x16x32_bf16(kfh[0][c0], qfh[s][c0], t0, 0, 0, 0);
        t0 = __builtin_amdgcn_mfma_f32_16x16x32_bf16(kfh[0][c0], qfl[s][c0], t0, 0, 0, 0);
        t0 = __builtin_amdgcn_mfma_f32_16x16x32_bf16(kfl[0][c0], qfh[s][c0], t0, 0, 0, 0);
        t1 = __builtin_amdgcn_mfma_f32_16x16x32_bf16(kfh[1][c0], qfh[s][c0], t1, 0, 0, 0);
        t1 = __builtin_amdgcn_mfma_f32_16x16x32_bf16(kfh[1][c0], qfl[s][c0], t1, 0, 0, 0);
        t1 = __builtin_amdgcn_mfma_f32_16x16x32_bf16(kfl[1][c0], qfh[s][c0], t1, 0, 0, 0);
      }
      a0[s] = t0; a1[s] = t1;
    }

    SCHED_FENCE();
    loadK(inext);
    SCHED_FENCE();

    // ---- softmax: exp2 + packed RNE, P hi-only
    #pragma unroll
    for (int s = 0; s < 4; ++s) {
      float p0 = EXP2(a0[s][0] - SHIFT2), p1 = EXP2(a0[s][1] - SHIFT2);
      float p2 = EXP2(a0[s][2] - SHIFT2), p3 = EXP2(a0[s][3] - SHIFT2);
      float p4 = EXP2(a1[s][0] - SHIFT2), p5 = EXP2(a1[s][1] - SHIFT2);
      float p6 = EXP2(a1[s][2] - SHIFT2), p7 = EXP2(a1[s][3] - SHIFT2);
      union { unsigned u[2]; short4 s4; } ua, ub;
      ua.u[0] = pk2(p0, p1); ua.u[1] = pk2(p2, p3);
      ub.u[0] = pk2(p4, p5); ub.u[1] = pk2(p6, p7);
      const int gbase = (s * 4 + (qq >> 1)) * 16 + l16;
      *(short4*)(P + (gbase * 8 + 4 * (qq & 1))) = ua.s4;
      *(short4*)(P + ((gbase + 32) * 8 + 4 * (qq & 1))) = ub.s4;
    }

    bf16x8 pf[4];
    #pragma unroll
    for (int s = 0; s < 4; ++s)
      pf[s] = *(const bf16x8*)(P + (((s * 4 + qq) * 16 + l16) * 8));

    // ---- O^T += Vh * P^T ; l += 1 * P
    #pragma unroll
    for (int ct = 0; ct < 4; ++ct)
      #pragma unroll
      for (int s = 0; s < 4; ++s)
        oacc[ct][s] = __builtin_amdgcn_mfma_f32_16x16x32_bf16(vfh[ct], pf[s], oacc[ct][s], 0, 0, 0);
    #pragma unroll
    for (int s = 0; s < 4; ++s)
      lacc[s] = __builtin_amdgcn_mfma_f32_16x16x32_bf16(onesA, pf[s], lacc[s], 0, 0, 0);

    SCHED_FENCE();
    loadV(inext);
    SCHED_FENCE();
  }

  // ---------------- in-block combine across the 8 m-eighths -----------------
  if (qq == 0) {
    #pragma unroll
    for (int s = 0; s < 4; ++s) LST[w * 64 + s * 16 + l16] = lacc[s][0];
  }
  __syncthreads();    // loop done; P region free for OC

  #pragma unroll
  for (int wp = 0; wp < 8; ++wp) {
    if (w == wp) {
      #pragma unroll
      for (int ct = 0; ct < 4; ++ct)
        #pragma unroll
        for (int s = 0; s < 4; ++s)
          #pragma unroll
          for (int r = 0; r < 4; ++r) {
            const int c = 16 * ct + 4 * qq + r;
            const int idx = c * 65 + 16 * s + l16;
            if (wp == 0) OC[idx] = oacc[ct][s][r];
            else         OC[idx] += oacc[ct][s][r];
          }
    }
    __syncthreads();
  }

  // final scale + coalesced store: 512 threads, 8 channels each
  {
    const int r  = tid & 63;
    const int cg = tid >> 6;          // 0..7
    float lsum = 0.f;
    #pragma unroll
    for (int w2 = 0; w2 < 8; ++w2)
      lsum += LST[w2 * 64 + (r >> 4) * 16 + (r & 15)];
    const float inv = 1.0f / lsum;
    #pragma unroll
    for (int u = 0; u < 8; ++u) {
      const int c = cg * 8 + u;
      ob[(size_t)c * NPIX + rb + r] = OC[c * 65 + r] * inv;
    }
  }
}

extern "C" void kernel_launch(void* const* d_in, const int* in_sizes, int n_in,
                              void* d_out, int out_size, void* d_ws, size_t ws_size,
                              hipStream_t stream) {
  const float* query  = (const float*)d_in[0];
  const float* keys   = (const float*)d_in[1];
  const float* values = (const float*)d_in[2];
  const float* Wq     = (const float*)d_in[3];
  const float* bq     = (const float*)d_in[4];
  short* ws = (short*)d_ws;           // 5*SZ*2 = 16.4 MB
  prep<<<dim3(1000), dim3(256), 0, stream>>>(query, keys, values, Wq, bq, ws);
  attn_main<<<dim3(400), dim3(512), 0, stream>>>(ws, (float*)d_out);
}

// Round 7
// 176.856 us; speedup vs baseline: 1.1597x; 1.0412x over previous
//
#include <hip/hip_runtime.h>
#include <hip/hip_bf16.h>

// CostAttention on MI355X — round 20: consolidation.
// R19 post-mortem: prep Wq->LDS staging WON (~15us: prep 78->63us inferred).
// attn_main Q-lo->registers REGRESSED (105->121us, Mfma 36->31): +32 VGPR of
// loop-invariant state cost more than the 8 ds_read_b128 it removed — LDS
// reads of loop-invariant operands are effectively free under MFMA chains
// here. KEEP prep (WQ staging); REVERT attn_main to R14 known-good (105us):
// QL in LDS, Q-hi in regs, smem 43008, (512,1).
// Next targets: prep still 6x off roofline (V-phase uncoalesced reads);
// attn_main MFMA starvation is structural (2 waves/SIMD pinned by 80-reg acc).
//
// ws layout: shorts [Qh][Ql][Kh][Kl][Vh], each SZ = 1,638,400 shorts (16.4MB).
//   Q/K chunk  ((b*400+mi)*2+c0)*512 + lane*8 : elem [r=16mi+l16][c=32c0+8qq+j]
//   V   chunk  (((b*100+i64)*8)+ct*2+mh)*512 + lane*8 : elem [c=16ct+l16][m=64i64+32mh+8qq+j]

#define NPIX 6400
#define SZ 1638400
#define SHIFT2 11.541560327111707f   // 8 * log2(e)

typedef float f32x4 __attribute__((ext_vector_type(4)));
typedef short bf16x8 __attribute__((ext_vector_type(8)));

#if defined(__has_builtin)
#if __has_builtin(__builtin_amdgcn_sched_barrier)
#define SCHED_FENCE() __builtin_amdgcn_sched_barrier(0)
#endif
#if __has_builtin(__builtin_amdgcn_exp2f)
#define EXP2(x) __builtin_amdgcn_exp2f(x)
#endif
#endif
#ifndef SCHED_FENCE
#define SCHED_FENCE()
#endif
#ifndef EXP2
#define EXP2(x) exp2f(x)
#endif

__device__ __forceinline__ void split2(float x, short& h, short& l) {
  unsigned xb = __float_as_uint(x);
  h = (short)(xb >> 16);
  float r = x - __uint_as_float(xb & 0xffff0000u);
  l = (short)(__float_as_uint(r) >> 16);
}

__device__ __forceinline__ short rne_bf16(float x) {
  unsigned u = __float_as_uint(x);
  return (short)((u + 0x7fffu + ((u >> 16) & 1u)) >> 16);
}

__device__ __forceinline__ unsigned pk2(float a, float b) {
  __hip_bfloat162 t = __float22bfloat162_rn(make_float2(a, b));
  unsigned r;
  __builtin_memcpy(&r, &t, 4);
  return r;
}

// ---------------- prep: stage -> LDS -> frag gather -------------------------
// grid 1000: [0,400) K (b,m-tile) | [400,800) Q-proj (b,r-tile) | [800,1000) V
// Wq staged in LDS for the Q phase (R19 win, kept).
__global__ __launch_bounds__(256, 2) void prep(
    const float* __restrict__ query, const float* __restrict__ keys,
    const float* __restrict__ values, const float* __restrict__ Wq,
    const float* __restrict__ bq, short* __restrict__ ws)
{
  const int tid = threadIdx.x;
  const int w = tid >> 6;
  const int lane = tid & 63, l16 = lane & 15, qq = lane >> 4;
  short* Qh = ws;          short* Ql = ws + SZ;
  short* Kh = ws + 2 * SZ; short* Kl = ws + 3 * SZ;
  short* Vh = ws + 4 * SZ;
  const int x = blockIdx.x;

  __shared__ float T[64 * 65];
  __shared__ float WQ[64 * 64];   // Q phase only; 16 KB

  if (x < 400) {                      // ---- K split (trunc hi/lo, 3-term S)
    const int b = x / 100, t64 = x % 100;
    const int m0 = t64 * 64;
    const float* kb = keys + (size_t)b * 64 * NPIX;
    {
      const int ch = tid >> 2, ml = (tid & 3) * 4;
      const float* src = kb + (size_t)ch * NPIX + m0 + ml;
      #pragma unroll
      for (int u = 0; u < 4; ++u)
        *(float4*)&T[ch * 65 + ml + 16 * u] = *(const float4*)(src + 16 * u);
    }
    __syncthreads();
    const int mi = t64 * 4 + w;
    #pragma unroll
    for (int c0 = 0; c0 < 2; ++c0) {
      float t[8];
      #pragma unroll
      for (int j = 0; j < 8; ++j)
        t[j] = T[(32 * c0 + 8 * qq + j) * 65 + 16 * w + l16];
      bf16x8 h8, l8;
      #pragma unroll
      for (int j = 0; j < 8; ++j) { short h, l; split2(t[j], h, l); h8[j] = h; l8[j] = l; }
      const int off = ((b * 400 + mi) * 2 + c0) * 512 + lane * 8;
      *(bf16x8*)(Kh + off) = h8;
      *(bf16x8*)(Kl + off) = l8;
    }
  } else if (x < 800) {               // ---- Q projection + trunc hi/lo split
    const int y = x - 400;
    const int b = y / 100, t64 = y % 100;
    const int r0 = t64 * 64;
    const float* qb = query + (size_t)b * 64 * NPIX;
    {
      const int ch = tid >> 2, ml = (tid & 3) * 4;
      const float* src = qb + (size_t)ch * NPIX + r0 + ml;
      #pragma unroll
      for (int u = 0; u < 4; ++u)
        *(float4*)&T[ch * 65 + ml + 16 * u] = *(const float4*)(src + 16 * u);
    }
    {   // stage Wq (64x64 f32) into LDS, coalesced
      const float4* wsrc = (const float4*)Wq;
      float4* wdst = (float4*)WQ;
      #pragma unroll
      for (int u = 0; u < 4; ++u)
        wdst[tid + 256 * u] = wsrc[tid + 256 * u];
    }
    __syncthreads();
    const int mi = t64 * 4 + w;

    float acc[2][8];
    #pragma unroll
    for (int c0 = 0; c0 < 2; ++c0)
      #pragma unroll
      for (int j = 0; j < 8; ++j) acc[c0][j] = 0.f;

    for (int cin4 = 0; cin4 < 64; cin4 += 4) {
      float xv[4];
      #pragma unroll
      for (int u = 0; u < 4; ++u)
        xv[u] = T[(cin4 + u) * 65 + 16 * w + l16];
      #pragma unroll
      for (int c0 = 0; c0 < 2; ++c0)
        #pragma unroll
        for (int j = 0; j < 8; ++j) {
          const float4 wv = *(const float4*)&WQ[(32 * c0 + 8 * qq + j) * 64 + cin4];
          acc[c0][j] += wv.x * xv[0] + wv.y * xv[1] + wv.z * xv[2] + wv.w * xv[3];
        }
    }
    #pragma unroll
    for (int c0 = 0; c0 < 2; ++c0) {
      bf16x8 h8, l8;
      #pragma unroll
      for (int j = 0; j < 8; ++j) {
        // scale = (1/8)*log2(e): S in log2 domain -> raw exp2 in main
        float v = (acc[c0][j] + bq[32 * c0 + 8 * qq + j]) * 0.18033688011112042f;
        short h, l; split2(v, h, l);
        h8[j] = h; l8[j] = l;
      }
      const int off = ((b * 400 + mi) * 2 + c0) * 512 + lane * 8;
      *(bf16x8*)(Qh + off) = h8;
      *(bf16x8*)(Ql + off) = l8;
    }
  } else {                            // ---- V: RNE bf16, hi only
    const int gw = (x - 800) * 4 + w;
    const int b = gw / 200, rest = gw % 200;
    const int i = rest / 2, half = rest % 2;
    const float* vb = values + (size_t)b * 64 * NPIX;
    #pragma unroll
    for (int cc = 0; cc < 2; ++cc) {
      const int ct = 2 * half + cc;
      #pragma unroll
      for (int mh = 0; mh < 2; ++mh) {
        const float* vp = vb + (size_t)(16 * ct + l16) * NPIX + 64 * i + 32 * mh + 8 * qq;
        const float4 a  = *(const float4*)vp;
        const float4 b4 = *(const float4*)(vp + 4);
        const float t[8] = {a.x, a.y, a.z, a.w, b4.x, b4.y, b4.z, b4.w};
        bf16x8 h8;
        #pragma unroll
        for (int j = 0; j < 8; ++j) h8[j] = rne_bf16(t[j]);
        const int off = (((b * 100 + i) * 8) + ct * 2 + mh) * 512 + lane * 8;
        *(bf16x8*)(Vh + off) = h8;
      }
    }
  }
}

// ---------------- main: 400 blocks x 512 thr; 8-wave in-block m-split -------
// R14 known-good structure (105us): Q-hi in regs, Q-lo in LDS (QL).
__global__ __launch_bounds__(512, 1) void attn_main(
    const short* __restrict__ ws, float* __restrict__ out)
{
  const int tid  = threadIdx.x;
  const int w    = tid >> 6;          // wave 0..7 = m-eighth
  const int lane = tid & 63;
  const int l16  = lane & 15, qq = lane >> 4;
  const int x = blockIdx.x;
  const int b      = x & 3;           // batch -> XCDs {b, b+4}; KV 2.4MB < L2
  const int rowjob = x >> 2;          // 0..99
  const int rb     = rowjob * 64;

  const short* Qh = ws;
  const short* Kh = ws + 2 * SZ;
  const short* Vh = ws + 4 * SZ;
  float* ob = out + (size_t)b * 64 * NPIX;

  // LDS: loop — per-wave P (8 x 4 KB) + shared Q-lo (8 KB) = 40 KB;
  // combine — OC [64][65] f32 (16640 B, aliases P) + LST (2 KB at 40960).
  __shared__ char smem[43008];
  short* P   = ((short*)smem) + (w << 11);   // wave-private 2048 shorts
  short* QL  = ((short*)smem) + 16384;       // shared Q-lo frags (8 KB)
  float* OC  = (float*)smem;
  float* LST = (float*)(smem + 40960);       // [8 waves][4 strips][16]

  bf16x8 qfh[4][2];
  {
    const short* qp = Qh + (size_t)((b * 400 + rowjob * 4) * 2) * 512 + lane * 8;
    #pragma unroll
    for (int s = 0; s < 4; ++s)
      #pragma unroll
      for (int c0 = 0; c0 < 2; ++c0) {
        qfh[s][c0] = *(const bf16x8*)(qp + (s * 2 + c0) * 512);
        *(bf16x8*)(QL + ((s * 2 + c0) * 64 + lane) * 8) =
            *(const bf16x8*)(qp + SZ + (s * 2 + c0) * 512);   // 8x redundant, benign
      }
  }
  __syncthreads();

  f32x4 zero4 = {0.f, 0.f, 0.f, 0.f};
  f32x4 oacc[4][4];
  f32x4 lacc[4];
  #pragma unroll
  for (int ct = 0; ct < 4; ++ct)
    #pragma unroll
    for (int s = 0; s < 4; ++s) oacc[ct][s] = zero4;
  #pragma unroll
  for (int s = 0; s < 4; ++s) lacc[s] = zero4;

  bf16x8 onesA;
  #pragma unroll
  for (int j = 0; j < 8; ++j) onesA[j] = (short)0x3F80;

  bf16x8 kfh[2][2], kfl[2][2];
  bf16x8 vfh[4];

  auto loadK = [&](int i2) {
    const short* kp = Kh + (size_t)((b * 400 + 2 * i2) * 2) * 512 + lane * 8;
    #pragma unroll
    for (int mt = 0; mt < 2; ++mt)
      #pragma unroll
      for (int c0 = 0; c0 < 2; ++c0) {
        kfh[mt][c0] = *(const bf16x8*)(kp + (mt * 2 + c0) * 512);
        kfl[mt][c0] = *(const bf16x8*)(kp + SZ + (mt * 2 + c0) * 512);
      }
  };
  auto loadV = [&](int i2) {
    const short* vp = Vh + (size_t)((b * 100 + (i2 >> 1)) * 8) * 512 + lane * 8;
    #pragma unroll
    for (int ct = 0; ct < 4; ++ct)
      vfh[ct] = *(const bf16x8*)(vp + (ct * 2 + (i2 & 1)) * 512);
  };

  // wave w owns m-chunks [25w, 25w+25) of 32 m each
  const int i0 = w * 25;
  loadK(i0);
  loadV(i0);

  for (int it = 0; it < 25; ++it) {
    const int i2 = i0 + it;
    const int inext = (it == 24) ? i0 : i2 + 1;

    // ---- all strips' S-MFMAs first (4 independent chains)
    f32x4 a0[4], a1[4];
    #pragma unroll
    for (int s = 0; s < 4; ++s) {
      f32x4 t0 = zero4, t1 = zero4;
      #pragma unroll
      for (int c0 = 0; c0 < 2; ++c0) {
        const bf16x8 ql = *(const bf16x8*)(QL + ((s * 2 + c0) * 64 + lane) * 8);
        t0 = __builtin_amdgcn_mfma_f32_16x16x32_bf16(kfh[0][c0], qfh[s][c0], t0, 0, 0, 0);
        t0 = __builtin_amdgcn_mfma_f32_16x16x32_bf16(kfh[0][c0], ql,         t0, 0, 0, 0);
        t0 = __builtin_amdgcn_mfma_f32_16x16x32_bf16(kfl[0][c0], qfh[s][c0], t0, 0, 0, 0);
        t1 = __builtin_amdgcn_mfma_f32_16x16x32_bf16(kfh[1][c0], qfh[s][c0], t1, 0, 0, 0);
        t1 = __builtin_amdgcn_mfma_f32_16x16x32_bf16(kfh[1][c0], ql,         t1, 0, 0, 0);
        t1 = __builtin_amdgcn_mfma_f32_16x16x32_bf16(kfl[1][c0], qfh[s][c0], t1, 0, 0, 0);
      }
      a0[s] = t0; a1[s] = t1;
    }

    SCHED_FENCE();
    loadK(inext);
    SCHED_FENCE();

    // ---- softmax: exp2 + packed RNE, P hi-only
    #pragma unroll
    for (int s = 0; s < 4; ++s) {
      float p0 = EXP2(a0[s][0] - SHIFT2), p1 = EXP2(a0[s][1] - SHIFT2);
      float p2 = EXP2(a0[s][2] - SHIFT2), p3 = EXP2(a0[s][3] - SHIFT2);
      float p4 = EXP2(a1[s][0] - SHIFT2), p5 = EXP2(a1[s][1] - SHIFT2);
      float p6 = EXP2(a1[s][2] - SHIFT2), p7 = EXP2(a1[s][3] - SHIFT2);
      union { unsigned u[2]; short4 s4; } ua, ub;
      ua.u[0] = pk2(p0, p1); ua.u[1] = pk2(p2, p3);
      ub.u[0] = pk2(p4, p5); ub.u[1] = pk2(p6, p7);
      const int gbase = (s * 4 + (qq >> 1)) * 16 + l16;
      *(short4*)(P + (gbase * 8 + 4 * (qq & 1))) = ua.s4;
      *(short4*)(P + ((gbase + 32) * 8 + 4 * (qq & 1))) = ub.s4;
    }

    bf16x8 pf[4];
    #pragma unroll
    for (int s = 0; s < 4; ++s)
      pf[s] = *(const bf16x8*)(P + (((s * 4 + qq) * 16 + l16) * 8));

    // ---- O^T += Vh * P^T ; l += 1 * P
    #pragma unroll
    for (int ct = 0; ct < 4; ++ct)
      #pragma unroll
      for (int s = 0; s < 4; ++s)
        oacc[ct][s] = __builtin_amdgcn_mfma_f32_16x16x32_bf16(vfh[ct], pf[s], oacc[ct][s], 0, 0, 0);
    #pragma unroll
    for (int s = 0; s < 4; ++s)
      lacc[s] = __builtin_amdgcn_mfma_f32_16x16x32_bf16(onesA, pf[s], lacc[s], 0, 0, 0);

    SCHED_FENCE();
    loadV(inext);
    SCHED_FENCE();
  }

  // ---------------- in-block combine across the 8 m-eighths -----------------
  if (qq == 0) {
    #pragma unroll
    for (int s = 0; s < 4; ++s) LST[w * 64 + s * 16 + l16] = lacc[s][0];
  }
  __syncthreads();    // loop done; P region free for OC

  #pragma unroll
  for (int wp = 0; wp < 8; ++wp) {
    if (w == wp) {
      #pragma unroll
      for (int ct = 0; ct < 4; ++ct)
        #pragma unroll
        for (int s = 0; s < 4; ++s)
          #pragma unroll
          for (int r = 0; r < 4; ++r) {
            const int c = 16 * ct + 4 * qq + r;
            const int idx = c * 65 + 16 * s + l16;
            if (wp == 0) OC[idx] = oacc[ct][s][r];
            else         OC[idx] += oacc[ct][s][r];
          }
    }
    __syncthreads();
  }

  // final scale + coalesced store: 512 threads, 8 channels each
  {
    const int r  = tid & 63;
    const int cg = tid >> 6;          // 0..7
    float lsum = 0.f;
    #pragma unroll
    for (int w2 = 0; w2 < 8; ++w2)
      lsum += LST[w2 * 64 + (r >> 4) * 16 + (r & 15)];
    const float inv = 1.0f / lsum;
    #pragma unroll
    for (int u = 0; u < 8; ++u) {
      const int c = cg * 8 + u;
      ob[(size_t)c * NPIX + rb + r] = OC[c * 65 + r] * inv;
    }
  }
}

extern "C" void kernel_launch(void* const* d_in, const int* in_sizes, int n_in,
                              void* d_out, int out_size, void* d_ws, size_t ws_size,
                              hipStream_t stream) {
  const float* query  = (const float*)d_in[0];
  const float* keys   = (const float*)d_in[1];
  const float* values = (const float*)d_in[2];
  const float* Wq     = (const float*)d_in[3];
  const float* bq     = (const float*)d_in[4];
  short* ws = (short*)d_ws;           // 5*SZ*2 = 16.4 MB
  prep<<<dim3(1000), dim3(256), 0, stream>>>(query, keys, values, Wq, bq, ws);
  attn_main<<<dim3(400), dim3(512), 0, stream>>>(ws, (float*)d_out);
}